// Round 11
// baseline (656.481 us; speedup 1.0000x reference)
//
#include <hip/hip_runtime.h>
#include <hip/hip_bf16.h>
#include <math.h>

#define NBATCH 8
#define NC 256
#define ND 32
#define SN 4096

// Workspace byte offsets
constexpr size_t VB_B   = 0;                      // 16 MB bf16 V [b][o][n]
constexpr size_t QT_B   = 16777216;               // 2 MB bf16 Q^T [b][n][d] (pre-scaled by log2e)
constexpr size_t KT_B   = QT_B + 2097152;         // 2 MB bf16 K^T [b][m][d]
constexpr size_t PM_B   = KT_B + 2097152;         // partial max (exp2 domain)
constexpr size_t PS_B   = PM_B + 32768;           // partial sum2
constexpr size_t C_B    = PS_B + 32768;           // 8 f32: C' = M' + log2(Z')
constexpr size_t WB_B   = C_B + 64;               // 320*256 bf16 packed weights
constexpr size_t BIAS_B = WB_B + 163840;          // 320 f32 biases

typedef __attribute__((ext_vector_type(8))) short short8;
typedef __attribute__((ext_vector_type(4))) float f32x4;

__device__ __forceinline__ unsigned bf16rne(float f) {
  unsigned u = __float_as_uint(f);
  return (u + 0x7fffu + ((u >> 16) & 1u)) >> 16;
}
__device__ __forceinline__ unsigned bfpack2(float lo, float hi) {
  union { __hip_bfloat162 h; unsigned u; } cv;
  cv.h.x = __float2bfloat16(lo);
  cv.h.y = __float2bfloat16(hi);
  return cv.u;
}

// ---------------------------------------------------------------------------
// Kernel 0: pack W1|W2*log2e|W3 -> bf16 Wb[320][256], biases -> f32[320]
// ---------------------------------------------------------------------------
__global__ __launch_bounds__(256) void prep_kernel(
    const float* __restrict__ W1, const float* __restrict__ b1,
    const float* __restrict__ W2, const float* __restrict__ b2,
    const float* __restrict__ W3, const float* __restrict__ b3,
    char* __restrict__ wsb)
{
  ushort* Wb = (ushort*)(wsb + WB_B);
  float* bias = (float*)(wsb + BIAS_B);
  const float LOG2E = 1.4426950408889634f;
  int idx = blockIdx.x * 256 + threadIdx.x;
  int r = idx >> 6, c4 = (idx & 63) * 4;
  float4 v; float sc = 1.0f;
  if (r < 256)      { v = *(const float4*)(W1 + (size_t)r * 256 + c4); }
  else if (r < 288) { v = *(const float4*)(W2 + (size_t)(r - 256) * 256 + c4); sc = LOG2E; }
  else              { v = *(const float4*)(W3 + (size_t)(r - 288) * 256 + c4); }
  ushort4 o;
  o.x = (ushort)bf16rne(v.x * sc); o.y = (ushort)bf16rne(v.y * sc);
  o.z = (ushort)bf16rne(v.z * sc); o.w = (ushort)bf16rne(v.w * sc);
  *(ushort4*)(Wb + (size_t)r * 256 + c4) = o;
  if (blockIdx.x == 0 && threadIdx.x < 320) {
    int q = threadIdx.x;
    bias[q] = q < 256 ? b1[q] : (q < 288 ? b2[q - 256] * LOG2E : b3[q - 288]);
  }
}

// ---------------------------------------------------------------------------
// Kernel 1: MFMA projections (unchanged)
// ---------------------------------------------------------------------------
__global__ __launch_bounds__(512) void proj_kernel(
    const float* __restrict__ x, char* __restrict__ wsb)
{
  __shared__ alignas(16) char xT[65536];    // [128 n][256 c] bf16, swz ((n&7)<<4)
  __shared__ alignas(16) char Wsh[40960];   // [320 o][64 c] bf16 chunk, swz ((o&7)<<4)
  const int bid = blockIdx.x;
  const int b = bid & 7, nt = bid >> 3;
  const int n0 = nt * 128;
  const int t = threadIdx.x, w = t >> 6, lane = t & 63;
  const int l4 = lane >> 4, l16 = lane & 15;
  const float* xb = x + (size_t)b * NC * SN;
  const ushort* Wb = (const ushort*)(wsb + WB_B);
  const float* bias = (const float*)(wsb + BIAS_B);
  ushort* vbuf  = (ushort*)(wsb + VB_B);
  ushort* qtbuf = (ushort*)(wsb + QT_B);
  ushort* ktbuf = (ushort*)(wsb + KT_B);

  {
    int cp = w * 16 + l16;
    int c  = cp * 2;
    int nb0 = l4 * 4;
#pragma unroll
    for (int ni = 0; ni < 8; ++ni) {
      int nB = ni * 16 + nb0;
      float4 a0 = *(const float4*)(xb + (size_t)c * SN + n0 + nB);
      float4 a1 = *(const float4*)(xb + (size_t)(c + 1) * SN + n0 + nB);
      const float* p0 = (const float*)&a0;
      const float* p1 = (const float*)&a1;
#pragma unroll
      for (int j = 0; j < 4; ++j) {
        int n = nB + j;
        *(uint*)(xT + n * 512 + ((cp * 4) ^ ((n & 7) << 4))) = bfpack2(p0[j], p1[j]);
      }
    }
  }
#pragma unroll
  for (int ii = 0; ii < 5; ++ii) {
    int slot = t + ii * 512;
    int r = slot >> 3, cc = slot & 7;
    *(uint4*)(Wsh + r * 128 + ((cc * 16) ^ ((r & 7) << 4))) =
        *(const uint4*)(Wb + (size_t)r * 256 + cc * 8);
  }
  __syncthreads();

  const int of_g = w >> 1;
  const int nf_g = w & 1;
  f32x4 acc[5][4] = {};

  for (int c4 = 0; c4 < 4; ++c4) {
#pragma unroll
    for (int kk = 0; kk < 2; ++kk) {
      short8 a[4];
#pragma unroll
      for (int nf = 0; nf < 4; ++nf) {
        int n = nf_g * 64 + nf * 16 + l16;
        a[nf] = *(const short8*)(xT + n * 512 +
                 ((c4 * 128 + kk * 64 + l4 * 16) ^ ((n & 7) << 4)));
      }
#pragma unroll
      for (int of = 0; of < 5; ++of) {
        int o = (of_g * 5 + of) * 16 + l16;
        short8 bf = *(const short8*)(Wsh + o * 128 +
                    ((kk * 64 + l4 * 16) ^ ((o & 7) << 4)));
#pragma unroll
        for (int nf = 0; nf < 4; ++nf)
          acc[of][nf] = __builtin_amdgcn_mfma_f32_16x16x32_bf16(a[nf], bf, acc[of][nf], 0, 0, 0);
      }
    }
    if (c4 < 3) {
      __syncthreads();
#pragma unroll
      for (int ii = 0; ii < 5; ++ii) {
        int slot = t + ii * 512;
        int r = slot >> 3, cc = slot & 7;
        *(uint4*)(Wsh + r * 128 + ((cc * 16) ^ ((r & 7) << 4))) =
            *(const uint4*)(Wb + (size_t)r * 256 + (c4 + 1) * 64 + cc * 8);
      }
      __syncthreads();
    }
  }

#pragma unroll
  for (int of = 0; of < 5; ++of) {
    int o = (of_g * 5 + of) * 16 + l16;
    float bv = bias[o];
#pragma unroll
    for (int nf = 0; nf < 4; ++nf) {
      int nb = nf_g * 64 + nf * 16 + l4 * 4;
      float v0 = acc[of][nf][0] + bv, v1 = acc[of][nf][1] + bv;
      float v2 = acc[of][nf][2] + bv, v3 = acc[of][nf][3] + bv;
      if (o < 256) {
        uint2 pk; pk.x = bfpack2(v0, v1); pk.y = bfpack2(v2, v3);
        *(uint2*)(vbuf + ((size_t)b * NC + o) * SN + n0 + nb) = pk;
      } else if (o < 288) {
        int d = o - 256;
        qtbuf[((size_t)b * SN + n0 + nb + 0) * ND + d] = (ushort)bf16rne(v0);
        qtbuf[((size_t)b * SN + n0 + nb + 1) * ND + d] = (ushort)bf16rne(v1);
        qtbuf[((size_t)b * SN + n0 + nb + 2) * ND + d] = (ushort)bf16rne(v2);
        qtbuf[((size_t)b * SN + n0 + nb + 3) * ND + d] = (ushort)bf16rne(v3);
      } else {
        int d = o - 288;
        ktbuf[((size_t)b * SN + n0 + nb + 0) * ND + d] = (ushort)bf16rne(v0);
        ktbuf[((size_t)b * SN + n0 + nb + 1) * ND + d] = (ushort)bf16rne(v1);
        ktbuf[((size_t)b * SN + n0 + nb + 2) * ND + d] = (ushort)bf16rne(v2);
        ktbuf[((size_t)b * SN + n0 + nb + 3) * ND + d] = (ushort)bf16rne(v3);
      }
    }
  }
}

// ---------------------------------------------------------------------------
// Kernel 2: QK^T tile stats in exp2 domain (unchanged)
// ---------------------------------------------------------------------------
__global__ __launch_bounds__(256) void qk_stats(
    const char* __restrict__ wsb, float* __restrict__ pm, float* __restrict__ ps)
{
  __shared__ alignas(16) char qt_s[128 * 64];
  __shared__ alignas(16) char kt_s[128 * 64];
  __shared__ float wm[4], wz[4];
  const int bid = blockIdx.x;
  const int b = bid & 7, ny = (bid >> 3) & 31, mx = bid >> 8;
  const int n0 = ny * 128, m0 = mx * 128;
  const int t = threadIdx.x, w = t >> 6, lane = t & 63;
  const int l4 = lane >> 4, l16 = lane & 15;
  const ushort* qtb = (const ushort*)(wsb + QT_B) + (size_t)b * SN * ND;
  const ushort* ktb = (const ushort*)(wsb + KT_B) + (size_t)b * SN * ND;
  {
    int row = t >> 1, db = (t & 1) * 32;
#pragma unroll
    for (int i = 0; i < 2; ++i) {
      int b16 = db + i * 16;
      int dst = row * 64 + (b16 ^ ((row & 3) << 4));
      *(uint4*)(qt_s + dst) = *(const uint4*)(qtb + (size_t)(n0 + row) * ND + b16 / 2);
      *(uint4*)(kt_s + dst) = *(const uint4*)(ktb + (size_t)(m0 + row) * ND + b16 / 2);
    }
  }
  __syncthreads();
  const f32x4 zf = {0.f, 0.f, 0.f, 0.f};
  short8 bfr[2];
#pragma unroll
  for (int j = 0; j < 2; ++j) {
    int mm = (w * 2 + j) * 16 + l16;
    bfr[j] = *(const short8*)(kt_s + mm * 64 + ((l4 * 16) ^ ((mm & 3) << 4)));
  }
  f32x4 sfr[8][2];
#pragma unroll
  for (int i = 0; i < 8; ++i) {
    int nn = i * 16 + l16;
    short8 af = *(const short8*)(qt_s + nn * 64 + ((l4 * 16) ^ ((nn & 3) << 4)));
#pragma unroll
    for (int j = 0; j < 2; ++j)
      sfr[i][j] = __builtin_amdgcn_mfma_f32_16x16x32_bf16(af, bfr[j], zf, 0, 0, 0);
  }
  float mt = -1e30f;
#pragma unroll
  for (int i = 0; i < 8; ++i)
#pragma unroll
    for (int j = 0; j < 2; ++j)
#pragma unroll
      for (int r = 0; r < 4; ++r) mt = fmaxf(mt, sfr[i][j][r]);
  float zt = 0.f;
#pragma unroll
  for (int i = 0; i < 8; ++i)
#pragma unroll
    for (int j = 0; j < 2; ++j)
#pragma unroll
      for (int r = 0; r < 4; ++r) zt += exp2f(sfr[i][j][r] - mt);

#pragma unroll
  for (int off = 1; off < 64; off <<= 1) {
    float m2 = __shfl_xor(mt, off);
    float z2 = __shfl_xor(zt, off);
    float M = fmaxf(mt, m2);
    zt = zt * exp2f(mt - M) + z2 * exp2f(m2 - M);
    mt = M;
  }
  if (lane == 0) { wm[w] = mt; wz[w] = zt; }
  __syncthreads();
  if (t == 0) {
    float m = wm[0], z = wz[0];
#pragma unroll
    for (int i = 1; i < 4; ++i) {
      float M = fmaxf(m, wm[i]);
      z = z * exp2f(m - M) + wz[i] * exp2f(wm[i] - M);
      m = M;
    }
    int idx = (b * 32 + ny) * 32 + mx;
    pm[idx] = m; ps[idx] = z;
  }
}

// ---------------------------------------------------------------------------
// Kernel 3: combine partials -> C'_b = M' + log2(Z')
// ---------------------------------------------------------------------------
__global__ __launch_bounds__(256) void reduce_kernel(char* __restrict__ wsb)
{
  const int b = blockIdx.x;
  const float* pm = (const float*)(wsb + PM_B) + (size_t)b * 1024;
  const float* ps = (const float*)(wsb + PS_B) + (size_t)b * 1024;
  const int t = threadIdx.x;
  float m = -1e30f, z = 0.f;
  for (int i = t; i < 1024; i += 256) {
    float m2 = pm[i], z2 = ps[i];
    float M = fmaxf(m, m2);
    z = z * exp2f(m - M) + z2 * exp2f(m2 - M);
    m = M;
  }
#pragma unroll
  for (int off = 1; off < 64; off <<= 1) {
    float m2 = __shfl_xor(m, off);
    float z2 = __shfl_xor(z, off);
    float M = fmaxf(m, m2);
    z = z * exp2f(m - M) + z2 * exp2f(m2 - M);
    m = M;
  }
  __shared__ float wm[4], wz[4];
  int w = t >> 6;
  if ((t & 63) == 0) { wm[w] = m; wz[w] = z; }
  __syncthreads();
  if (t == 0) {
    float M = wm[0], Z = wz[0];
#pragma unroll
    for (int i = 1; i < 4; ++i) {
      float Mn = fmaxf(M, wm[i]);
      Z = Z * exp2f(M - Mn) + wz[i] * exp2f(wm[i] - Mn);
      M = Mn;
    }
    ((float*)(wsb + C_B))[b] = M + log2f(Z);
  }
}

// ---------------------------------------------------------------------------
// Kernel 4: attention output — wave-autonomous, barrier-free main loop.
// Block = 8 waves, 512 thr. Wave w owns m-frag (mt*8+w)*16 and ALL 256 o.
// Per 64-n chunk per wave:
//   S: 4 MFMAs (Q from global, C-init = -Cb), exp2, pack, write P (8B x4)
//      to PRIVATE LDS slice (program-order lgkmcnt, no barrier).
//   PV: 2 conflict-free 16B P reads + 32 MFMAs, V direct from global (L1/L2).
// __syncthreads() per chunk is PACING only (keeps 32KB V slab L1-shared);
// carries no data dependency, so PV never waits on other waves' S.
// Grid 256 = 8 b x 32 mt; b = bid&7 -> batch pinned to one XCD's L2.
// ---------------------------------------------------------------------------
__global__ __launch_bounds__(512) void attn_out(
    const char* __restrict__ wsb, const float* __restrict__ x, float* __restrict__ out)
{
  __shared__ alignas(16) char p_s[16384];   // 8 waves x 2KB private P slices
  const int bid = blockIdx.x;
  const int b = bid & 7, mt = bid >> 3;     // 8 batches x 32 m-tiles (128 m)
  const int t = threadIdx.x, w = t >> 6, lane = t & 63;
  const int l4 = lane >> 4, l16 = lane & 15;
  const ushort* vb  = (const ushort*)(wsb + VB_B) + (size_t)b * NC * SN;
  const ushort* qtb = (const ushort*)(wsb + QT_B) + (size_t)b * SN * ND;
  const ushort* ktb = (const ushort*)(wsb + KT_B) + (size_t)b * SN * ND;
  const float Cb = ((const float*)(wsb + C_B))[b];

  const int m0 = mt * 128 + w * 16;         // this wave's 16 m-columns
  // K fragment (resident): lane = K[m0+l16][l4*8..+7]
  short8 bfr = *(const short8*)(ktb + (size_t)(m0 + l16) * ND + l4 * 8);
  const f32x4 cinit = {-Cb, -Cb, -Cb, -Cb};

  char* myp = p_s + w * 2048;               // private P slice
  // P write base: for nf -> addr = (nf>>1)*1024 + (2*(nf&1)+(l4>>1))*256
  //                                + l16*16 + (l4&1)*8   [derived & checked]
  const int pw_base = l16 * 16 + (l4 & 1) * 8;
  const int l4h = l4 >> 1;

  // V row base: lane reads V[o=of*16+l16][n=..+l4*8]
  const ushort* vrow = vb + (size_t)l16 * SN + l4 * 8;

  f32x4 acc[16];
#pragma unroll
  for (int of = 0; of < 16; ++of) acc[of] = (f32x4){0.f, 0.f, 0.f, 0.f};

  for (int i = 0; i < 64; ++i) {
    const int n0 = i * 64;
    // ---- S phase: 4 n-frags, Q direct from global (L1-shared across waves)
#pragma unroll
    for (int nf = 0; nf < 4; ++nf) {
      short8 af = *(const short8*)(qtb + (size_t)(n0 + nf * 16 + l16) * ND + l4 * 8);
      f32x4 sv = __builtin_amdgcn_mfma_f32_16x16x32_bf16(af, bfr, cinit, 0, 0, 0);
      uint2 pk;
      pk.x = bfpack2(exp2f(sv[0]), exp2f(sv[1]));
      pk.y = bfpack2(exp2f(sv[2]), exp2f(sv[3]));
      *(uint2*)(myp + (nf >> 1) * 1024 + (2 * (nf & 1) + l4h) * 256 + pw_base) = pk;
    }
    // ---- PV phase: own-wave P (no barrier), V from global
    __builtin_amdgcn_s_setprio(1);
#pragma unroll
    for (int kk = 0; kk < 2; ++kk) {
      short8 paf = *(const short8*)(myp + kk * 1024 + lane * 16);
      const ushort* vkk = vrow + n0 + kk * 32;
#pragma unroll
      for (int of = 0; of < 16; ++of) {
        short8 vf = *(const short8*)(vkk + (size_t)(of * 16) * SN);
        acc[of] = __builtin_amdgcn_mfma_f32_16x16x32_bf16(vf, paf, acc[of], 0, 0, 0);
      }
    }
    __builtin_amdgcn_s_setprio(0);
    __syncthreads();   // pacing only: keep waves' V slabs co-resident in L1
  }

  // epilogue: out = acc + x ; D layout: col m=l16, row o = of*16 + l4*4 + j
#pragma unroll
  for (int of = 0; of < 16; ++of) {
#pragma unroll
    for (int j = 0; j < 4; ++j) {
      int o = of * 16 + l4 * 4 + j;
      size_t idx = ((size_t)b * NC + o) * SN + m0 + l16;
      out[idx] = acc[of][j] + x[idx];
    }
  }
}

extern "C" void kernel_launch(void* const* d_in, const int* in_sizes, int n_in,
                              void* d_out, int out_size, void* d_ws, size_t ws_size,
                              hipStream_t stream)
{
  const float* x  = (const float*)d_in[0];
  const float* W1 = (const float*)d_in[1];
  const float* b1 = (const float*)d_in[2];
  const float* W2 = (const float*)d_in[3];
  const float* b2 = (const float*)d_in[4];
  const float* W3 = (const float*)d_in[5];
  const float* b3 = (const float*)d_in[6];
  char* wsb  = (char*)d_ws;
  float* out = (float*)d_out;

  prep_kernel<<<80, 256, 0, stream>>>(W1, b1, W2, b2, W3, b3, wsb);
  proj_kernel<<<256, 512, 0, stream>>>(x, wsb);
  qk_stats<<<8192, 256, 0, stream>>>(wsb, (float*)(wsb + PM_B), (float*)(wsb + PS_B));
  reduce_kernel<<<NBATCH, 256, 0, stream>>>(wsb);
  attn_out<<<256, 512, 0, stream>>>(wsb, x, out);
}

// Round 12
// 221.459 us; speedup vs baseline: 2.9643x; 2.9643x over previous
//
#include <hip/hip_runtime.h>
#include <hip/hip_bf16.h>
#include <math.h>

#define NBATCH 8
#define NC 256
#define ND 32
#define SN 4096

// Workspace byte offsets
constexpr size_t VB_B   = 0;                      // 16 MB bf16 V [b][o][n]
constexpr size_t QT_B   = 16777216;               // 2 MB bf16 Q^T [b][n][d] (pre-scaled by log2e)
constexpr size_t KT_B   = QT_B + 2097152;         // 2 MB bf16 K^T [b][m][d]
constexpr size_t PM_B   = KT_B + 2097152;         // partial max (exp2 domain)
constexpr size_t PS_B   = PM_B + 32768;           // partial sum2
constexpr size_t C_B    = PS_B + 32768;           // 8 f32: C' = M' + log2(Z')
constexpr size_t WB_B   = C_B + 64;               // 320*256 bf16 packed weights
constexpr size_t BIAS_B = WB_B + 163840;          // 320 f32 biases
constexpr size_t PB_B   = BIAS_B + 1280;          // 16.7 MB bf16 partial O (n-half 0)

typedef __attribute__((ext_vector_type(8))) short short8;
typedef __attribute__((ext_vector_type(4))) float f32x4;

__device__ __forceinline__ unsigned bf16rne(float f) {
  unsigned u = __float_as_uint(f);
  return (u + 0x7fffu + ((u >> 16) & 1u)) >> 16;
}
__device__ __forceinline__ unsigned bfpack2(float lo, float hi) {
  union { __hip_bfloat162 h; unsigned u; } cv;
  cv.h.x = __float2bfloat16(lo);
  cv.h.y = __float2bfloat16(hi);
  return cv.u;
}

// ---------------------------------------------------------------------------
// Kernel 0: pack W1|W2*log2e|W3 -> bf16 Wb[320][256], biases -> f32[320]
// ---------------------------------------------------------------------------
__global__ __launch_bounds__(256) void prep_kernel(
    const float* __restrict__ W1, const float* __restrict__ b1,
    const float* __restrict__ W2, const float* __restrict__ b2,
    const float* __restrict__ W3, const float* __restrict__ b3,
    char* __restrict__ wsb)
{
  ushort* Wb = (ushort*)(wsb + WB_B);
  float* bias = (float*)(wsb + BIAS_B);
  const float LOG2E = 1.4426950408889634f;
  int idx = blockIdx.x * 256 + threadIdx.x;
  int r = idx >> 6, c4 = (idx & 63) * 4;
  float4 v; float sc = 1.0f;
  if (r < 256)      { v = *(const float4*)(W1 + (size_t)r * 256 + c4); }
  else if (r < 288) { v = *(const float4*)(W2 + (size_t)(r - 256) * 256 + c4); sc = LOG2E; }
  else              { v = *(const float4*)(W3 + (size_t)(r - 288) * 256 + c4); }
  ushort4 o;
  o.x = (ushort)bf16rne(v.x * sc); o.y = (ushort)bf16rne(v.y * sc);
  o.z = (ushort)bf16rne(v.z * sc); o.w = (ushort)bf16rne(v.w * sc);
  *(ushort4*)(Wb + (size_t)r * 256 + c4) = o;
  if (blockIdx.x == 0 && threadIdx.x < 320) {
    int q = threadIdx.x;
    bias[q] = q < 256 ? b1[q] : (q < 288 ? b2[q - 256] * LOG2E : b3[q - 288]);
  }
}

// ---------------------------------------------------------------------------
// Kernel 1: MFMA projections (unchanged)
// ---------------------------------------------------------------------------
__global__ __launch_bounds__(512) void proj_kernel(
    const float* __restrict__ x, char* __restrict__ wsb)
{
  __shared__ alignas(16) char xT[65536];    // [128 n][256 c] bf16, swz ((n&7)<<4)
  __shared__ alignas(16) char Wsh[40960];   // [320 o][64 c] bf16 chunk, swz ((o&7)<<4)
  const int bid = blockIdx.x;
  const int b = bid & 7, nt = bid >> 3;
  const int n0 = nt * 128;
  const int t = threadIdx.x, w = t >> 6, lane = t & 63;
  const int l4 = lane >> 4, l16 = lane & 15;
  const float* xb = x + (size_t)b * NC * SN;
  const ushort* Wb = (const ushort*)(wsb + WB_B);
  const float* bias = (const float*)(wsb + BIAS_B);
  ushort* vbuf  = (ushort*)(wsb + VB_B);
  ushort* qtbuf = (ushort*)(wsb + QT_B);
  ushort* ktbuf = (ushort*)(wsb + KT_B);

  {
    int cp = w * 16 + l16;
    int c  = cp * 2;
    int nb0 = l4 * 4;
#pragma unroll
    for (int ni = 0; ni < 8; ++ni) {
      int nB = ni * 16 + nb0;
      float4 a0 = *(const float4*)(xb + (size_t)c * SN + n0 + nB);
      float4 a1 = *(const float4*)(xb + (size_t)(c + 1) * SN + n0 + nB);
      const float* p0 = (const float*)&a0;
      const float* p1 = (const float*)&a1;
#pragma unroll
      for (int j = 0; j < 4; ++j) {
        int n = nB + j;
        *(uint*)(xT + n * 512 + ((cp * 4) ^ ((n & 7) << 4))) = bfpack2(p0[j], p1[j]);
      }
    }
  }
#pragma unroll
  for (int ii = 0; ii < 5; ++ii) {
    int slot = t + ii * 512;
    int r = slot >> 3, cc = slot & 7;
    *(uint4*)(Wsh + r * 128 + ((cc * 16) ^ ((r & 7) << 4))) =
        *(const uint4*)(Wb + (size_t)r * 256 + cc * 8);
  }
  __syncthreads();

  const int of_g = w >> 1;
  const int nf_g = w & 1;
  f32x4 acc[5][4] = {};

  for (int c4 = 0; c4 < 4; ++c4) {
#pragma unroll
    for (int kk = 0; kk < 2; ++kk) {
      short8 a[4];
#pragma unroll
      for (int nf = 0; nf < 4; ++nf) {
        int n = nf_g * 64 + nf * 16 + l16;
        a[nf] = *(const short8*)(xT + n * 512 +
                 ((c4 * 128 + kk * 64 + l4 * 16) ^ ((n & 7) << 4)));
      }
#pragma unroll
      for (int of = 0; of < 5; ++of) {
        int o = (of_g * 5 + of) * 16 + l16;
        short8 bf = *(const short8*)(Wsh + o * 128 +
                    ((kk * 64 + l4 * 16) ^ ((o & 7) << 4)));
#pragma unroll
        for (int nf = 0; nf < 4; ++nf)
          acc[of][nf] = __builtin_amdgcn_mfma_f32_16x16x32_bf16(a[nf], bf, acc[of][nf], 0, 0, 0);
      }
    }
    if (c4 < 3) {
      __syncthreads();
#pragma unroll
      for (int ii = 0; ii < 5; ++ii) {
        int slot = t + ii * 512;
        int r = slot >> 3, cc = slot & 7;
        *(uint4*)(Wsh + r * 128 + ((cc * 16) ^ ((r & 7) << 4))) =
            *(const uint4*)(Wb + (size_t)r * 256 + (c4 + 1) * 64 + cc * 8);
      }
      __syncthreads();
    }
  }

#pragma unroll
  for (int of = 0; of < 5; ++of) {
    int o = (of_g * 5 + of) * 16 + l16;
    float bv = bias[o];
#pragma unroll
    for (int nf = 0; nf < 4; ++nf) {
      int nb = nf_g * 64 + nf * 16 + l4 * 4;
      float v0 = acc[of][nf][0] + bv, v1 = acc[of][nf][1] + bv;
      float v2 = acc[of][nf][2] + bv, v3 = acc[of][nf][3] + bv;
      if (o < 256) {
        uint2 pk; pk.x = bfpack2(v0, v1); pk.y = bfpack2(v2, v3);
        *(uint2*)(vbuf + ((size_t)b * NC + o) * SN + n0 + nb) = pk;
      } else if (o < 288) {
        int d = o - 256;
        qtbuf[((size_t)b * SN + n0 + nb + 0) * ND + d] = (ushort)bf16rne(v0);
        qtbuf[((size_t)b * SN + n0 + nb + 1) * ND + d] = (ushort)bf16rne(v1);
        qtbuf[((size_t)b * SN + n0 + nb + 2) * ND + d] = (ushort)bf16rne(v2);
        qtbuf[((size_t)b * SN + n0 + nb + 3) * ND + d] = (ushort)bf16rne(v3);
      } else {
        int d = o - 288;
        ktbuf[((size_t)b * SN + n0 + nb + 0) * ND + d] = (ushort)bf16rne(v0);
        ktbuf[((size_t)b * SN + n0 + nb + 1) * ND + d] = (ushort)bf16rne(v1);
        ktbuf[((size_t)b * SN + n0 + nb + 2) * ND + d] = (ushort)bf16rne(v2);
        ktbuf[((size_t)b * SN + n0 + nb + 3) * ND + d] = (ushort)bf16rne(v3);
      }
    }
  }
}

// ---------------------------------------------------------------------------
// Kernel 2: QK^T tile stats in exp2 domain (unchanged)
// ---------------------------------------------------------------------------
__global__ __launch_bounds__(256) void qk_stats(
    const char* __restrict__ wsb, float* __restrict__ pm, float* __restrict__ ps)
{
  __shared__ alignas(16) char qt_s[128 * 64];
  __shared__ alignas(16) char kt_s[128 * 64];
  __shared__ float wm[4], wz[4];
  const int bid = blockIdx.x;
  const int b = bid & 7, ny = (bid >> 3) & 31, mx = bid >> 8;
  const int n0 = ny * 128, m0 = mx * 128;
  const int t = threadIdx.x, w = t >> 6, lane = t & 63;
  const int l4 = lane >> 4, l16 = lane & 15;
  const ushort* qtb = (const ushort*)(wsb + QT_B) + (size_t)b * SN * ND;
  const ushort* ktb = (const ushort*)(wsb + KT_B) + (size_t)b * SN * ND;
  {
    int row = t >> 1, db = (t & 1) * 32;
#pragma unroll
    for (int i = 0; i < 2; ++i) {
      int b16 = db + i * 16;
      int dst = row * 64 + (b16 ^ ((row & 3) << 4));
      *(uint4*)(qt_s + dst) = *(const uint4*)(qtb + (size_t)(n0 + row) * ND + b16 / 2);
      *(uint4*)(kt_s + dst) = *(const uint4*)(ktb + (size_t)(m0 + row) * ND + b16 / 2);
    }
  }
  __syncthreads();
  const f32x4 zf = {0.f, 0.f, 0.f, 0.f};
  short8 bfr[2];
#pragma unroll
  for (int j = 0; j < 2; ++j) {
    int mm = (w * 2 + j) * 16 + l16;
    bfr[j] = *(const short8*)(kt_s + mm * 64 + ((l4 * 16) ^ ((mm & 3) << 4)));
  }
  f32x4 sfr[8][2];
#pragma unroll
  for (int i = 0; i < 8; ++i) {
    int nn = i * 16 + l16;
    short8 af = *(const short8*)(qt_s + nn * 64 + ((l4 * 16) ^ ((nn & 3) << 4)));
#pragma unroll
    for (int j = 0; j < 2; ++j)
      sfr[i][j] = __builtin_amdgcn_mfma_f32_16x16x32_bf16(af, bfr[j], zf, 0, 0, 0);
  }
  float mt = -1e30f;
#pragma unroll
  for (int i = 0; i < 8; ++i)
#pragma unroll
    for (int j = 0; j < 2; ++j)
#pragma unroll
      for (int r = 0; r < 4; ++r) mt = fmaxf(mt, sfr[i][j][r]);
  float zt = 0.f;
#pragma unroll
  for (int i = 0; i < 8; ++i)
#pragma unroll
    for (int j = 0; j < 2; ++j)
#pragma unroll
      for (int r = 0; r < 4; ++r) zt += exp2f(sfr[i][j][r] - mt);

#pragma unroll
  for (int off = 1; off < 64; off <<= 1) {
    float m2 = __shfl_xor(mt, off);
    float z2 = __shfl_xor(zt, off);
    float M = fmaxf(mt, m2);
    zt = zt * exp2f(mt - M) + z2 * exp2f(m2 - M);
    mt = M;
  }
  if (lane == 0) { wm[w] = mt; wz[w] = zt; }
  __syncthreads();
  if (t == 0) {
    float m = wm[0], z = wz[0];
#pragma unroll
    for (int i = 1; i < 4; ++i) {
      float M = fmaxf(m, wm[i]);
      z = z * exp2f(m - M) + wz[i] * exp2f(wm[i] - M);
      m = M;
    }
    int idx = (b * 32 + ny) * 32 + mx;
    pm[idx] = m; ps[idx] = z;
  }
}

// ---------------------------------------------------------------------------
// Kernel 3: combine partials -> C'_b = M' + log2(Z')
// ---------------------------------------------------------------------------
__global__ __launch_bounds__(256) void reduce_kernel(char* __restrict__ wsb)
{
  const int b = blockIdx.x;
  const float* pm = (const float*)(wsb + PM_B) + (size_t)b * 1024;
  const float* ps = (const float*)(wsb + PS_B) + (size_t)b * 1024;
  const int t = threadIdx.x;
  float m = -1e30f, z = 0.f;
  for (int i = t; i < 1024; i += 256) {
    float m2 = pm[i], z2 = ps[i];
    float M = fmaxf(m, m2);
    z = z * exp2f(m - M) + z2 * exp2f(m2 - M);
    m = M;
  }
#pragma unroll
  for (int off = 1; off < 64; off <<= 1) {
    float m2 = __shfl_xor(m, off);
    float z2 = __shfl_xor(z, off);
    float M = fmaxf(m, m2);
    z = z * exp2f(m - M) + z2 * exp2f(m2 - M);
    m = M;
  }
  __shared__ float wm[4], wz[4];
  int w = t >> 6;
  if ((t & 63) == 0) { wm[w] = m; wz[w] = z; }
  __syncthreads();
  if (t == 0) {
    float M = wm[0], Z = wz[0];
#pragma unroll
    for (int i = 1; i < 4; ++i) {
      float Mn = fmaxf(M, wm[i]);
      Z = Z * exp2f(M - Mn) + wz[i] * exp2f(wm[i] - Mn);
      M = Mn;
    }
    ((float*)(wsb + C_B))[b] = M + log2f(Z);
  }
}

// ---------------------------------------------------------------------------
// Kernel 4: attention output. 4-wave block = 256 o x 64 m x 2048 n (n-split 2),
// chunk n=64, grid 1024 (8 b x 64 mt x 2 halves) -> 4 independent
// barrier-groups / CU (phase diversity, NO work duplication).
// Per chunk per wave: S = 4 MFMA (own m-frag w, -C folded into C-init),
// PV = 32 MFMA over own 64-o slice x all 64 m.
// Frag-major LDS; qt staged per-wave (1KB contiguous global, lane*16 LDS).
// half 0 -> bf16 partial; half 1 -> f32 out; combine adds + skip.
// ---------------------------------------------------------------------------
__global__ __launch_bounds__(256, 4) void attn_out(
    char* __restrict__ wsb, float* __restrict__ out)
{
  __shared__ alignas(16) char qt_s[2][4096];   // 4 frags x 1KB, dbuf
  __shared__ alignas(16) char as_s[2][8192];   // 8 frags x 1KB, dbuf
  const int bid = blockIdx.x;
  const int b = bid & 7;
  const int rest = bid >> 3;
  const int mt = rest & 63;
  const int half = rest >> 6;
  const int m0 = mt * 64;
  const int nbase = half * 2048;
  const int t = threadIdx.x, w = t >> 6, lane = t & 63;
  const int l4 = lane >> 4, l16 = lane & 15;
  const ushort* vb  = (const ushort*)(wsb + VB_B) + (size_t)b * NC * SN;
  const ushort* qtb = (const ushort*)(wsb + QT_B) + (size_t)b * SN * ND;
  const ushort* ktb = (const ushort*)(wsb + KT_B) + (size_t)b * SN * ND;
  const float Cb = ((const float*)(wsb + C_B))[b];

  // S role: wave w owns m-frag w
  short8 bfr = *(const short8*)(ktb + (size_t)(m0 + w * 16 + l16) * ND + l4 * 8);
  const f32x4 cinit = {-Cb, -Cb, -Cb, -Cb};

  // as_s frag-major write base (round-10-verified mapping, mfS = w)
  const int as_wb = w * 1024 + l16 * 16 + (l4 & 1) * 8;
  const int l4h = l4 >> 1;

  // qt staging: wave w stages frag w; global = contiguous 1KB/wave,
  // LDS = lane*16 (conflict-free both sides)
  const int qrow = w * 16 + l16;           // n-row within chunk
  const int qt_addr = w * 1024 + lane * 16;

  // PV: wave owns o-slice [w*64, w*64+64)
  const ushort* vrow = vb + (size_t)(w * 64 + l16) * SN + nbase + l4 * 8;

  f32x4 acc[4][4] = {};

  // prologue: stage qt chunk 0 of this half
  *(uint4*)(qt_s[0] + qt_addr) = *(const uint4*)(qtb + (size_t)(nbase + qrow) * ND + l4 * 8);
  __syncthreads();

  for (int i = 0; i < 32; ++i) {
    const int cur = i & 1;
    // V loads for this chunk (drained by the barrier; consumed in PV)
    short8 vf[2][4];
#pragma unroll
    for (int kk = 0; kk < 2; ++kk)
#pragma unroll
      for (int of = 0; of < 4; ++of)
        vf[kk][of] = *(const short8*)(vrow + (size_t)(of * 16) * SN + i * 64 + kk * 32);
    // q^T prefetch for next chunk
    uint4 qnext;
    const bool pf = (i < 31);
    if (pf) qnext = *(const uint4*)(qtb + (size_t)(nbase + (i + 1) * 64 + qrow) * ND + l4 * 8);

    // S phase: 4 n-frags for this wave's m-frag; -C folded into C-init
#pragma unroll
    for (int nf = 0; nf < 4; ++nf) {
      short8 af = *(const short8*)(qt_s[cur] + nf * 1024 + lane * 16);
      f32x4 sv = __builtin_amdgcn_mfma_f32_16x16x32_bf16(af, bfr, cinit, 0, 0, 0);
      uint2 pk;
      pk.x = bfpack2(exp2f(sv[0]), exp2f(sv[1]));
      pk.y = bfpack2(exp2f(sv[2]), exp2f(sv[3]));
      int addr = (nf >> 1) * 4096 + (((nf & 1) * 2 + l4h) & 3) * 256 + as_wb;
      *(uint2*)(as_s[cur] + addr) = pk;
    }
    if (pf)
      *(uint4*)(qt_s[cur ^ 1] + qt_addr) = qnext;
    __syncthreads();

    // PV phase: 32 MFMAs, conflict-free frag-major reads
    __builtin_amdgcn_s_setprio(1);
#pragma unroll
    for (int kk = 0; kk < 2; ++kk) {
#pragma unroll
      for (int mf = 0; mf < 4; ++mf) {
        short8 paf = *(const short8*)(as_s[cur] + (kk * 4 + mf) * 1024 + lane * 16);
#pragma unroll
        for (int of = 0; of < 4; ++of)
          acc[of][mf] = __builtin_amdgcn_mfma_f32_16x16x32_bf16(vf[kk][of], paf, acc[of][mf], 0, 0, 0);
      }
    }
    __builtin_amdgcn_s_setprio(0);
  }

  // epilogue: half 0 -> bf16 partial; half 1 -> raw f32 to out
  if (half == 0) {
    ushort* pb = (ushort*)(wsb + PB_B);
#pragma unroll
    for (int of = 0; of < 4; ++of)
#pragma unroll
      for (int mf = 0; mf < 4; ++mf) {
        int m = m0 + mf * 16 + l16;
#pragma unroll
        for (int j = 0; j < 4; ++j) {
          int o = w * 64 + of * 16 + l4 * 4 + j;
          pb[((size_t)b * NC + o) * SN + m] = (ushort)bf16rne(acc[of][mf][j]);
        }
      }
  } else {
#pragma unroll
    for (int of = 0; of < 4; ++of)
#pragma unroll
      for (int mf = 0; mf < 4; ++mf) {
        int m = m0 + mf * 16 + l16;
#pragma unroll
        for (int j = 0; j < 4; ++j) {
          int o = w * 64 + of * 16 + l4 * 4 + j;
          out[((size_t)b * NC + o) * SN + m] = acc[of][mf][j];
        }
      }
  }
}

// ---------------------------------------------------------------------------
// Kernel 5: combine halves + skip: out = out + bf16(PB) + x
// ---------------------------------------------------------------------------
__global__ __launch_bounds__(256) void combine_kernel(
    const char* __restrict__ wsb, const float* __restrict__ x, float* __restrict__ out)
{
  const ushort* pb = (const ushort*)(wsb + PB_B);
  const size_t total = (size_t)NBATCH * NC * SN;
  for (size_t i = ((size_t)blockIdx.x * 256 + threadIdx.x) * 4; i < total;
       i += (size_t)gridDim.x * 256 * 4) {
    float4 o = *(const float4*)(out + i);
    ushort4 p = *(const ushort4*)(pb + i);
    float4 xx = *(const float4*)(x + i);
    o.x += __uint_as_float((unsigned)p.x << 16) + xx.x;
    o.y += __uint_as_float((unsigned)p.y << 16) + xx.y;
    o.z += __uint_as_float((unsigned)p.z << 16) + xx.z;
    o.w += __uint_as_float((unsigned)p.w << 16) + xx.w;
    *(float4*)(out + i) = o;
  }
}

extern "C" void kernel_launch(void* const* d_in, const int* in_sizes, int n_in,
                              void* d_out, int out_size, void* d_ws, size_t ws_size,
                              hipStream_t stream)
{
  const float* x  = (const float*)d_in[0];
  const float* W1 = (const float*)d_in[1];
  const float* b1 = (const float*)d_in[2];
  const float* W2 = (const float*)d_in[3];
  const float* b2 = (const float*)d_in[4];
  const float* W3 = (const float*)d_in[5];
  const float* b3 = (const float*)d_in[6];
  char* wsb  = (char*)d_ws;
  float* out = (float*)d_out;

  prep_kernel<<<80, 256, 0, stream>>>(W1, b1, W2, b2, W3, b3, wsb);
  proj_kernel<<<256, 512, 0, stream>>>(x, wsb);
  qk_stats<<<8192, 256, 0, stream>>>(wsb, (float*)(wsb + PM_B), (float*)(wsb + PS_B));
  reduce_kernel<<<NBATCH, 256, 0, stream>>>(wsb);
  attn_out<<<1024, 256, 0, stream>>>(wsb, out);
  combine_kernel<<<2048, 256, 0, stream>>>(wsb, x, out);
}